// Round 7
// baseline (50.322 us; speedup 1.0000x reference)
//
#include <hip/hip_runtime.h>
#include <cstdint>

#define B_ROWS 4096
#define N_ROWS 8192
#define D_DIM  256
#define TGRID  64                  // 8192 / 128 col tiles
#define TIPS   32                  // 8192 / 256 row panels
#define NBLOCKS 1056               // sum_{tip<32} (64-2*tip)
#define BK     32                  // K-step
#define NKT    8                   // 256 / 32

typedef __attribute__((ext_vector_type(4))) float f32x4;
typedef __attribute__((ext_vector_type(8))) short bf16x8;
typedef __attribute__((ext_vector_type(4))) unsigned short u16x4;

__device__ __forceinline__ unsigned short f2bf(float f) {
    union { float f; unsigned u; } v; v.f = f;
    unsigned r = v.u + 0x7FFF + ((v.u >> 16) & 1);   // RNE
    return (unsigned short)(r >> 16);
}
__device__ __forceinline__ float bf2f(unsigned short h) {
    union { unsigned u; float f; } v; v.u = ((unsigned)h) << 16;
    return v.f;
}

__device__ __forceinline__ void gload16(const void* g, void* l) {
    __builtin_amdgcn_global_load_lds(
        (const __attribute__((address_space(1))) void*)g,
        (__attribute__((address_space(3))) void*)l, 16, 0, 0);
}

__device__ __forceinline__ f32x4 exp4(f32x4 v) {
    f32x4 r;
    r.x = __expf(v.x); r.y = __expf(v.y); r.z = __expf(v.z); r.w = __expf(v.w);
    return r;
}

// ------------- Kernel A: normalize both pair rows + pos dot, one pass -------------
__global__ __launch_bounds__(256) void normpos_kernel(const float* __restrict__ zi,
                                                      const float* __restrict__ zj,
                                                      unsigned short* __restrict__ zn,
                                                      float* __restrict__ pospartial) {
    int wid = threadIdx.x >> 6;
    int lane = threadIdx.x & 63;
    int p = blockIdx.x * 4 + wid;          // 0..B_ROWS-1
    f32x4 ga = *(const f32x4*)(zi + (size_t)p * D_DIM + lane * 4);
    f32x4 gb = *(const f32x4*)(zj + (size_t)p * D_DIM + lane * 4);
    float sa = ga.x * ga.x + ga.y * ga.y + ga.z * ga.z + ga.w * ga.w;
    float sb = gb.x * gb.x + gb.y * gb.y + gb.z * gb.z + gb.w * gb.w;
    #pragma unroll
    for (int m = 1; m < 64; m <<= 1) { sa += __shfl_xor(sa, m, 64); sb += __shfl_xor(sb, m, 64); }
    float fa = 1.41421356237309515f / fmaxf(sqrtf(sa), 1e-8f);
    float fb = 1.41421356237309515f / fmaxf(sqrtf(sb), 1e-8f);
    u16x4 oa, ob;
    oa.x = f2bf(ga.x * fa); oa.y = f2bf(ga.y * fa); oa.z = f2bf(ga.z * fa); oa.w = f2bf(ga.w * fa);
    ob.x = f2bf(gb.x * fb); ob.y = f2bf(gb.y * fb); ob.z = f2bf(gb.z * fb); ob.w = f2bf(gb.w * fb);
    *(u16x4*)(zn + (size_t)p * D_DIM + lane * 4) = oa;
    *(u16x4*)(zn + (size_t)(p + B_ROWS) * D_DIM + lane * 4) = ob;
    float d = bf2f(oa.x) * bf2f(ob.x) + bf2f(oa.y) * bf2f(ob.y)
            + bf2f(oa.z) * bf2f(ob.z) + bf2f(oa.w) * bf2f(ob.w);
    #pragma unroll
    for (int m = 1; m < 64; m <<= 1) d += __shfl_xor(d, m, 64);
    if (lane == 0) pospartial[p] = d;
}

// ------------- Kernel C: 256x128 block (M=2 row-tiles x N=1 col-tile), upper triangle -------------
// 4 waves 2x2, wave-tile 128x64 (acc 8x4), BK=32, 3-buffer LDS, counted vmcnt(6),
// one raw s_barrier per K-step, 2 blocks/CU. Swizzle: chunk ^= (row>>1)&3 (verified).
// Per 128x128 sub-tile (r,c): r<c -> row+col sums; r==c -> row only; r>c -> discard.
__global__ __launch_bounds__(256, 2) void simclr_gemm_kernel(const unsigned short* __restrict__ zn,
                                                             float* __restrict__ P) {
    __shared__ unsigned short As[3][256 * BK];   // 3 x 16 KB
    __shared__ unsigned short Bs[3][128 * BK];   // 3 x 8 KB
    __shared__ float rPpart[2][256];             // per-wc row partials (256 rows)
    __shared__ float cPpart[2][128];             // per-wr col partials (128 cols)

    const int tid = threadIdx.x;
    const int lane = tid & 63, wid = tid >> 6;
    const int wr = wid >> 1, wc = wid & 1;       // 2x2 wave grid

    // XCD-bijective swizzle (1056 % 8 == 0)
    int bid = (int)((blockIdx.x & 7) * (NBLOCKS / 8) + (blockIdx.x >> 3));
    // decode bid -> (tip, tj): tip in [0,32), tj in [2*tip, 64); start(tip) = tip*(65-tip)
    int tip = (int)((65.0f - sqrtf(4225.0f - 4.0f * (float)bid)) * 0.5f);
    if (tip > 31) tip = 31;
    while ((tip + 1) * (65 - (tip + 1)) <= bid) ++tip;
    while (tip * (65 - tip) > bid) --tip;
    const int tj = 2 * tip + (bid - tip * (65 - tip));

    const char* gA = (const char*)zn + (size_t)tip * 256 * 512;   // 256-row panel
    const char* gB = (const char*)zn + (size_t)tj * 128 * 512;    // 128-row panel

    // staging: A = 256 rows x 64 B (4 issues), B = 128 rows x 64 B (2 issues), 16B/thread each.
    // thread -> (row = q*64 + tid>>2, slot = tid&3); LDS linear; source chunk pre-swizzled:
    // sch = slot ^ ((row>>1)&3) = (tid&3) ^ ((tid>>3)&3)  (q*64 doesn't affect (row>>1)&3).
    const int r0 = tid >> 2;
    const int sch = (tid & 3) ^ ((tid >> 3) & 3);
    const size_t gbase = (size_t)r0 * 512 + (size_t)sch * 16;
    const unsigned lo = (unsigned)tid * 8;       // ushort index (byte tid*16)

    f32x4 acc[8][4];
    #pragma unroll
    for (int m = 0; m < 8; ++m)
        #pragma unroll
        for (int n = 0; n < 4; ++n)
            acc[m][n] = (f32x4){0.f, 0.f, 0.f, 0.f};

#define STAGE(buf_, kt_) do {                                         \
    size_t kb = (size_t)(kt_) * 64;                                   \
    gload16(gA + gbase + kb,              &As[buf_][lo]);             \
    gload16(gA + gbase + 64 * 512 + kb,   &As[buf_][2048u + lo]);     \
    gload16(gA + gbase + 128 * 512 + kb,  &As[buf_][4096u + lo]);     \
    gload16(gA + gbase + 192 * 512 + kb,  &As[buf_][6144u + lo]);     \
    gload16(gB + gbase + kb,              &Bs[buf_][lo]);             \
    gload16(gB + gbase + 64 * 512 + kb,   &Bs[buf_][2048u + lo]);     \
} while (0)

    STAGE(0, 0);
    STAGE(1, 1);

    // frag read: row r -> lds k-chunk kc = (lane>>4) ^ ((r>>1)&3); frag row bases x16
    const int kc = (lane >> 4) ^ (((lane & 15) >> 1) & 3);
    const int arow = wr * 128 + (lane & 15);
    const int brow = wc * 64 + (lane & 15);

    #pragma unroll
    for (int kt = 0; kt < NKT; ++kt) {
        const int cur = kt % 3;
        if (kt < NKT - 1) asm volatile("s_waitcnt vmcnt(6)" ::: "memory");
        else              asm volatile("s_waitcnt vmcnt(0)" ::: "memory");
        __builtin_amdgcn_sched_barrier(0);
        __builtin_amdgcn_s_barrier();
        __builtin_amdgcn_sched_barrier(0);

        bf16x8 af[8], bfr[4];
        #pragma unroll
        for (int m = 0; m < 8; ++m)
            af[m] = *(const bf16x8*)&As[cur][(arow + m * 16) * 32 + kc * 8];
        #pragma unroll
        for (int n = 0; n < 4; ++n)
            bfr[n] = *(const bf16x8*)&Bs[cur][(brow + n * 16) * 32 + kc * 8];

        __builtin_amdgcn_s_setprio(1);
        #pragma unroll
        for (int m = 0; m < 8; ++m)
            #pragma unroll
            for (int n = 0; n < 4; ++n)
                acc[m][n] = __builtin_amdgcn_mfma_f32_16x16x32_bf16(af[m], bfr[n], acc[m][n], 0, 0, 0);
        __builtin_amdgcn_s_setprio(0);

        // pin: no gload_lds may hoist above the MFMA/ds_read cluster (overwrite hazard)
        __builtin_amdgcn_sched_barrier(0);
        if (kt < NKT - 2) STAGE((kt + 2) % 3, kt + 2);
    }
#undef STAGE

    // ---- epilogue: exp; unique-writer LDS partials (no atomics) ----
    float cs[4] = {0.f, 0.f, 0.f, 0.f};
    #pragma unroll
    for (int m = 0; m < 8; ++m) {
        f32x4 ef[4];
        #pragma unroll
        for (int n = 0; n < 4; ++n) ef[n] = exp4(acc[m][n]);
        f32x4 rv = ef[0] + ef[1] + ef[2] + ef[3];
        #pragma unroll
        for (int msk = 1; msk <= 8; msk <<= 1) {
            rv.x += __shfl_xor(rv.x, msk, 64);
            rv.y += __shfl_xor(rv.y, msk, 64);
            rv.z += __shfl_xor(rv.z, msk, 64);
            rv.w += __shfl_xor(rv.w, msk, 64);
        }
        if ((lane & 15) == 0) {
            int rbase = wr * 128 + m * 16 + (lane >> 4) * 4;
            rPpart[wc][rbase + 0] = rv.x;
            rPpart[wc][rbase + 1] = rv.y;
            rPpart[wc][rbase + 2] = rv.z;
            rPpart[wc][rbase + 3] = rv.w;
        }
        #pragma unroll
        for (int n = 0; n < 4; ++n)
            cs[n] += ef[n].x + ef[n].y + ef[n].z + ef[n].w;
    }
    #pragma unroll
    for (int n = 0; n < 4; ++n) {
        float c = cs[n];
        c += __shfl_xor(c, 16, 64);
        c += __shfl_xor(c, 32, 64);
        if (lane < 16) cPpart[wr][wc * 64 + n * 16 + lane] = c;
    }
    __syncthreads();

    // row-sums: source slot tj, panel tip rows (256). Discard wr=1 half iff tj==2*tip.
    {
        float rs = rPpart[0][tid] + rPpart[1][tid];
        if (tj == 2 * tip && tid >= 128) rs = 0.f;
        P[(size_t)tj * N_ROWS + (size_t)tip * 256 + tid] = rs;
    }
    // col-sums: source slot 64+tip, tile tj rows (128). Include sub-tile iff tj > r_tile.
    if (tid < 128) {
        float s0 = (tj > 2 * tip)     ? cPpart[0][tid] : 0.f;
        float s1 = (tj > 2 * tip + 1) ? cPpart[1][tid] : 0.f;
        P[(size_t)(64 + tip) * N_ROWS + (size_t)tj * 128 + tid] = s0 + s1;
    }
}

// ------------- Kernel E: per-row reduce (variable sources) + log (+fold pos) -------------
__global__ __launch_bounds__(256) void reduce_rows_kernel(const float* __restrict__ P,
                                                          const float* __restrict__ pospartial,
                                                          float* __restrict__ blockpart) {
    const float E2 = 7.38905609893065f;   // exp(self-sim) = e^2
    int row = blockIdx.x * 256 + threadIdx.x;
    int tip = row >> 8;                   // 256-row panel (== blockIdx.x)
    int tjr = row >> 7;                   // 128-row tile
    float s = 0.f;
    #pragma unroll 4
    for (int src = 2 * tip; src < TGRID; ++src)
        s += P[(size_t)src * N_ROWS + row];
    #pragma unroll 4
    for (int sc = 0; sc <= (tjr >> 1); ++sc)
        s += P[(size_t)(64 + sc) * N_ROWS + row];
    float v = logf(s - E2);
    if (threadIdx.x < 128)
        v -= 2.0f * pospartial[blockIdx.x * 128 + threadIdx.x];
    #pragma unroll
    for (int m = 1; m < 64; m <<= 1) v += __shfl_xor(v, m, 64);
    __shared__ float ws[4];
    if ((threadIdx.x & 63) == 0) ws[threadIdx.x >> 6] = v;
    __syncthreads();
    if (threadIdx.x == 0) blockpart[blockIdx.x] = ws[0] + ws[1] + ws[2] + ws[3];
}

// ------------- Kernel F: out = sum(blockpart) / N -------------
__global__ __launch_bounds__(64) void final_kernel(const float* __restrict__ blockpart,
                                                   float* __restrict__ out) {
    int lane = threadIdx.x;
    float v = (lane < TIPS) ? blockpart[lane] : 0.f;
    #pragma unroll
    for (int m = 1; m < 64; m <<= 1) v += __shfl_xor(v, m, 64);
    if (lane == 0) out[0] = v / (float)N_ROWS;
}

extern "C" void kernel_launch(void* const* d_in, const int* in_sizes, int n_in,
                              void* d_out, int out_size, void* d_ws, size_t ws_size,
                              hipStream_t stream) {
    const float* zi = (const float*)d_in[0];
    const float* zj = (const float*)d_in[1];
    char* ws = (char*)d_ws;
    unsigned short* zn = (unsigned short*)ws;                        // 4 MB
    float* P = (float*)(ws + 4 * 1024 * 1024);                       // 3 MB (96 x 8192 f32)
    float* pospartial = (float*)(ws + 8 * 1024 * 1024);              // 16 KB
    float* blockpart = (float*)(ws + 8 * 1024 * 1024 + 16 * 1024);   // 128 B

    normpos_kernel<<<B_ROWS / 4, 256, 0, stream>>>(zi, zj, zn, pospartial);
    simclr_gemm_kernel<<<NBLOCKS, 256, 0, stream>>>(zn, P);
    reduce_rows_kernel<<<TIPS, 256, 0, stream>>>(P, pospartial, blockpart);
    final_kernel<<<1, 64, 0, stream>>>(blockpart, (float*)d_out);
}